// Round 2
// baseline (180.281 us; speedup 1.0000x reference)
//
#include <hip/hip_runtime.h>
#include <hip/hip_cooperative_groups.h>
#include <math.h>

namespace cg = cooperative_groups;

#define BS 8
#define NPTS 16384
#define C 32
#define K 256
#define KNNK 16
#define NBINS 512
#define BINW 0.00025f
#define CAP 4096
#define NSPL 64          // point-splits per graph in k_logits

typedef float f32x4 __attribute__((ext_vector_type(4)));
typedef __bf16 bf16x8 __attribute__((ext_vector_type(8)));
union U16x8 { int4 i; bf16x8 v; unsigned short u[8]; };

// ---------------------------------------------------------------------------
// Phase 1: MFMA logit GEMM + exp + weighted position accumulation.
// Split-bf16: L = A_lo*B_hi + A_hi*B_lo + A_hi*B_hi (fp32 MFMA accum);
// verified: identical KNN sets vs fp32 path. Pooling head (W_pool) unused:
// its logit term is constant over n and cancels in the per-graph softmax.
// ---------------------------------------------------------------------------
__global__ __launch_bounds__(256, 2) void k_logits(
    const float* __restrict__ f, const float* __restrict__ pos,
    const float* __restrict__ Wr, float* __restrict__ partials) {
  int b = blockIdx.x >> 6;          // 64 blocks per graph
  int r = blockIdx.x & 63;
  int pbase = b * NPTS + r * 256;
  int t = threadIdx.x;
  int w = t >> 6, lane = t & 63;
  int h = w & 1, nh = w >> 1;
  int quad = lane >> 4, col = lane & 15;

  __shared__ float4 posLDS[256];
  __shared__ float4 fm[2][256];

  // stage pos chunk (256 pts x 12 B) -> padded float4 via LDS repack
  float* rawf = (float*)&fm[0][0];
  if (t < 192) ((float4*)rawf)[t] = ((const float4*)(pos + (size_t)pbase * 3))[t];
  __syncthreads();
  float4 myp = make_float4(rawf[t * 3], rawf[t * 3 + 1], rawf[t * 3 + 2], 0.f);
  __syncthreads();
  posLDS[t] = myp;

  // B fragments for this wave's kp-half (8 tiles), direct fp32 load + split.
  U16x8 Bh[8], Bl[8];
#pragma unroll
  for (int jt = 0; jt < 8; jt++) {
    int tile = h * 8 + jt;
#pragma unroll
    for (int j = 0; j < 8; j++) {
      float v = Wr[(quad * 8 + j) * K + tile * 16 + col];
      unsigned u = __float_as_uint(v);
      unsigned hb = u >> 16;
      float hf = __uint_as_float(hb << 16);
      unsigned lb = __float_as_uint(v - hf) >> 16;
      Bh[jt].u[j] = (unsigned short)hb;
      Bl[jt].u[j] = (unsigned short)lb;
    }
  }
  float acce[8], accx[8], accy[8], accz[8];
#pragma unroll
  for (int jt = 0; jt < 8; jt++) { acce[jt] = 0.f; accx[jt] = 0.f; accy[jt] = 0.f; accz[jt] = 0.f; }

#pragma unroll 1
  for (int nt = nh * 8; nt < nh * 8 + 8; nt++) {
    const float* fb = f + ((size_t)(pbase + nt * 16 + col)) * C + quad * 8;
    float4 a0 = *(const float4*)fb;
    float4 a1 = *(const float4*)(fb + 4);
    float av[8] = {a0.x, a0.y, a0.z, a0.w, a1.x, a1.y, a1.z, a1.w};
    U16x8 Ah, Al;
#pragma unroll
    for (int j = 0; j < 8; j++) {
      unsigned u = __float_as_uint(av[j]);
      unsigned hb = u >> 16;
      float hf = __uint_as_float(hb << 16);
      unsigned lb = __float_as_uint(av[j] - hf) >> 16;
      Ah.u[j] = (unsigned short)hb;
      Al.u[j] = (unsigned short)lb;
    }
    float4 pr0 = posLDS[nt * 16 + quad * 4 + 0];
    float4 pr1 = posLDS[nt * 16 + quad * 4 + 1];
    float4 pr2 = posLDS[nt * 16 + quad * 4 + 2];
    float4 pr3 = posLDS[nt * 16 + quad * 4 + 3];
#pragma unroll
    for (int jt = 0; jt < 8; jt++) {
      f32x4 d = {0.f, 0.f, 0.f, 0.f};
      d = __builtin_amdgcn_mfma_f32_16x16x32_bf16(Al.v, Bh[jt].v, d, 0, 0, 0);
      d = __builtin_amdgcn_mfma_f32_16x16x32_bf16(Ah.v, Bl[jt].v, d, 0, 0, 0);
      d = __builtin_amdgcn_mfma_f32_16x16x32_bf16(Ah.v, Bh[jt].v, d, 0, 0, 0);
      // C/D layout: col=lane&15 (kp), row=quad*4+reg (pt)  [m89-verified]
      float e0 = __expf(d[0]), e1 = __expf(d[1]), e2 = __expf(d[2]), e3 = __expf(d[3]);
      acce[jt] += (e0 + e1) + (e2 + e3);
      accx[jt] += e0 * pr0.x + e1 * pr1.x + e2 * pr2.x + e3 * pr3.x;
      accy[jt] += e0 * pr0.y + e1 * pr1.y + e2 * pr2.y + e3 * pr3.y;
      accz[jt] += e0 * pr0.z + e1 * pr1.z + e2 * pr2.z + e3 * pr3.z;
    }
  }

#pragma unroll
  for (int jt = 0; jt < 8; jt++) {
    acce[jt] += __shfl_xor(acce[jt], 16); acce[jt] += __shfl_xor(acce[jt], 32);
    accx[jt] += __shfl_xor(accx[jt], 16); accx[jt] += __shfl_xor(accx[jt], 32);
    accy[jt] += __shfl_xor(accy[jt], 16); accy[jt] += __shfl_xor(accy[jt], 32);
    accz[jt] += __shfl_xor(accz[jt], 16); accz[jt] += __shfl_xor(accz[jt], 32);
  }
  __syncthreads();
  if (lane < 16) {
#pragma unroll
    for (int jt = 0; jt < 8; jt++)
      fm[nh][h * 128 + jt * 16 + lane] = make_float4(acce[jt], accx[jt], accy[jt], accz[jt]);
  }
  __syncthreads();
  float4 v0 = fm[0][t], v1 = fm[1][t];
  float4* po = (float4*)partials;
  po[(size_t)blockIdx.x * 256 + t] =
      make_float4(v0.x + v1.x, v0.y + v1.y, v0.z + v1.z, v0.w + v1.w);
}

// ---------------------------------------------------------------------------
// Phase 2 (cooperative, 128 blocks x 256 thr = 16 sub-blocks/graph):
//   M. merge 64 split-partials -> 16 keypoints per block (coalesced)
//   C. (sb==0) centroid + max keypoint-centroid distance
//   H. histogram of d2(point, centroid); points REGISTER-CACHED across sync
//   R. parallel prefix-scan radius select: T >= d16(centroid);
//      R = T + 2*maxdiam (triangle-ineq exact); degenerate -> R=inf fallback
//   D. compact candidates from registers (no pos re-read)
//   T. exact top-16 per keypoint (16 kp/block), indices stay in LDS
//   E. fused extract: gather 16 rows, mean, 32x32 linear -> out
// Dependencies enforced with 4 grid.sync()s; dispatch count 6 -> 2.
// ---------------------------------------------------------------------------
__global__ __launch_bounds__(256) void k_coop(
    const float* __restrict__ pos, const float* __restrict__ f,
    const float* __restrict__ We, const float* __restrict__ partials,
    float* __restrict__ kpts, float* __restrict__ gstat,
    unsigned* __restrict__ ghist, unsigned* __restrict__ ccnt,
    float4* __restrict__ cand, float* __restrict__ out) {
  cg::grid_group grid = cg::this_grid();
  int blk = blockIdx.x;
  int g = blk >> 4;      // graph
  int sb = blk & 15;     // sub-block within graph
  int t = threadIdx.x;
  int lane = t & 63, wave = t >> 6;

  __shared__ float4 red[16][17];
  __shared__ float bc[4];
  __shared__ float wred[4][4];
  __shared__ unsigned hist[NBINS];
  __shared__ unsigned sc[NBINS];
  __shared__ int mbin;
  __shared__ int nidx[16][KNNK];
  __shared__ float P[16][C + 1];

  // ---- zero global scratch (before first sync; atomics all happen after) ----
  if (t < 32) ghist[blk * 32 + t] = 0;
  if (blk == 0 && t < BS) ccnt[t] = 0;

  // ---- M: merge partials -> this block's 16 keypoints ----
  {
    int kpl = t & 15, sg = t >> 4;
    const float4* po = (const float4*)partials;
    int kp = sb * 16 + kpl;
    float4 s = make_float4(0.f, 0.f, 0.f, 0.f);
#pragma unroll
    for (int k2 = 0; k2 < 4; k2++) {
      float4 v = po[((size_t)(g * NSPL + sg + k2 * 16)) * 256 + kp];
      s.x += v.x; s.y += v.y; s.z += v.z; s.w += v.w;
    }
    red[sg][kpl] = s;
  }
  __syncthreads();
  if (t < 16) {
    float L = 0.f, x = 0.f, y = 0.f, z = 0.f;
#pragma unroll
    for (int sg = 0; sg < 16; sg++) {
      float4 v = red[sg][t];
      L += v.x; x += v.y; y += v.z; z += v.w;
    }
    float inv = 1.f / L;
    ((float4*)kpts)[g * 256 + sb * 16 + t] = make_float4(x * inv, y * inv, z * inv, 0.f);
  }
  grid.sync();

  // ---- C: centroid + maxd (one block per graph) ----
  if (sb == 0) {
    float4 kpt = ((const float4*)kpts)[g * 256 + t];
    float sx = kpt.x, sy = kpt.y, sz = kpt.z;
#pragma unroll
    for (int off = 32; off; off >>= 1) {
      sx += __shfl_xor(sx, off, 64);
      sy += __shfl_xor(sy, off, 64);
      sz += __shfl_xor(sz, off, 64);
    }
    if (lane == 0) { wred[wave][0] = sx; wred[wave][1] = sy; wred[wave][2] = sz; }
    __syncthreads();
    if (t == 0) {
      float X = 0.f, Y = 0.f, Z = 0.f;
#pragma unroll
      for (int i = 0; i < 4; i++) { X += wred[i][0]; Y += wred[i][1]; Z += wred[i][2]; }
      bc[0] = X / K; bc[1] = Y / K; bc[2] = Z / K;
    }
    __syncthreads();
    float cx = bc[0], cy = bc[1], cz = bc[2];
    float dx = kpt.x - cx, dy = kpt.y - cy, dz = kpt.z - cz;
    float md = dx * dx + dy * dy + dz * dz;
#pragma unroll
    for (int off = 32; off; off >>= 1) md = fmaxf(md, __shfl_xor(md, off, 64));
    if (lane == 0) wred[wave][3] = md;
    __syncthreads();
    if (t == 0) {
      float m = fmaxf(fmaxf(wred[0][3], wred[1][3]), fmaxf(wred[2][3], wred[3][3]));
      ((float4*)gstat)[g] = make_float4(cx, cy, cz, sqrtf(m));
    }
  }
  grid.sync();

  // ---- H: histogram; register-cache this thread's 4 points ----
  float4 st = ((const float4*)gstat)[g];
  hist[t] = 0; hist[t + 256] = 0;
  __syncthreads();
  float px[4], py[4], pz[4], pd[4];
#pragma unroll
  for (int i = 0; i < 4; i++) {
    int pl = sb * 1024 + i * 256 + t;
    const float* pp = pos + (size_t)(g * NPTS + pl) * 3;
    px[i] = pp[0]; py[i] = pp[1]; pz[i] = pp[2];
    float dx = px[i] - st.x, dy = py[i] - st.y, dz = pz[i] - st.z;
    pd[i] = dx * dx + dy * dy + dz * dz;
    int bin = (int)(pd[i] * (1.0f / BINW));
    if (bin < NBINS - 1) atomicAdd(&hist[bin], 1u);
  }
  __syncthreads();
  {
    unsigned v0 = hist[t], v1 = hist[t + 256];
    if (v0) atomicAdd(&ghist[g * NBINS + t], v0);
    if (v1) atomicAdd(&ghist[g * NBINS + t + 256], v1);
  }
  grid.sync();

  // ---- R: parallel inclusive scan of hist -> first bin with cum >= 16 ----
  sc[t] = ghist[g * NBINS + t];
  sc[t + 256] = ghist[g * NBINS + t + 256];
  if (t == 0) mbin = NBINS - 1;   // sentinel
  __syncthreads();
  for (int off = 1; off < NBINS; off <<= 1) {
    unsigned a0 = (t >= off) ? sc[t - off] : 0u;
    unsigned a1 = ((t + 256) >= off) ? sc[t + 256 - off] : 0u;
    __syncthreads();
    sc[t] += a0; sc[t + 256] += a1;
    __syncthreads();
  }
  {
    unsigned c0 = sc[t], p0 = t ? sc[t - 1] : 0u;
    unsigned c1 = sc[t + 256], p1 = sc[t + 255];
    if (c0 >= KNNK && p0 < KNNK) atomicMin(&mbin, t);
    if ((t + 256) < (NBINS - 1) && c1 >= KNNK && p1 < KNNK) atomicMin(&mbin, t + 256);
  }
  __syncthreads();
  float r2;
  if (mbin < NBINS - 1) {
    float Rf = sqrtf((mbin + 1) * BINW) + 2.f * st.w;
    r2 = Rf * Rf;
  } else r2 = 3.0e38f;

  // ---- D: compact candidates from register cache (no pos re-read) ----
#pragma unroll
  for (int i = 0; i < 4; i++) {
    if (pd[i] <= r2) {
      int pl = sb * 1024 + i * 256 + t;
      unsigned u = atomicAdd(&ccnt[g], 1u);
      if (u < CAP) cand[(size_t)g * CAP + u] = make_float4(px[i], py[i], pz[i], __int_as_float(pl));
    }
  }
  grid.sync();

  // ---- T: exact top-16 for this block's 16 keypoints ----
  unsigned cnt = ccnt[g];
  int ovf = cnt > CAP;
  if (t < 16) {
    float4 kpt = ((const float4*)kpts)[g * 256 + sb * 16 + t];
    float kx = kpt.x, ky = kpt.y, kz = kpt.z;
    float dd[KNNK]; int ii[KNNK];
#pragma unroll
    for (int j = 0; j < KNNK; j++) { dd[j] = 1e30f; ii[j] = 0; }
    float mx = 1e30f;
    if (!ovf) {
      int n = (int)cnt;
      for (int j = 0; j < n; j++) {
        float4 v = cand[(size_t)g * CAP + j];
        float dx = kx - v.x, dy = ky - v.y, dz = kz - v.z;
        float d2 = dx * dx + dy * dy + dz * dz;
        if (d2 < mx) {
          int sm = 0; float bv = dd[0];
#pragma unroll
          for (int s = 1; s < KNNK; s++) if (dd[s] > bv) { bv = dd[s]; sm = s; }
#pragma unroll
          for (int s = 0; s < KNNK; s++) if (s == sm) { dd[s] = d2; ii[s] = __float_as_int(v.w); }
          mx = dd[0];
#pragma unroll
          for (int s = 1; s < KNNK; s++) mx = fmaxf(mx, dd[s]);
        }
      }
    } else {
      for (int j = 0; j < NPTS; j++) {
        const float* pp = pos + (size_t)(g * NPTS + j) * 3;
        float dx = kx - pp[0], dy = ky - pp[1], dz = kz - pp[2];
        float d2 = dx * dx + dy * dy + dz * dz;
        if (d2 < mx) {
          int sm = 0; float bv = dd[0];
#pragma unroll
          for (int s = 1; s < KNNK; s++) if (dd[s] > bv) { bv = dd[s]; sm = s; }
#pragma unroll
          for (int s = 0; s < KNNK; s++) if (s == sm) { dd[s] = d2; ii[s] = j; }
          mx = dd[0];
#pragma unroll
          for (int s = 1; s < KNNK; s++) mx = fmaxf(mx, dd[s]);
        }
      }
    }
#pragma unroll
    for (int j = 0; j < KNNK; j++) nidx[t][j] = ii[j];
  }
  __syncthreads();

  // ---- E: fused extract (gather 16 rows, mean, 32x32 linear) ----
  {
    int c = t & 31, kl = t >> 5;   // kl in 0..7, two keypoints per thread
#pragma unroll
    for (int hh = 0; hh < 2; hh++) {
      int kp = kl + hh * 8;
      float s = 0.f;
#pragma unroll
      for (int j = 0; j < KNNK; j++) {
        int pl = nidx[kp][j];
        s += f[((size_t)(g * NPTS + pl)) * C + c];
      }
      P[kp][c] = s * (1.f / KNNK);
    }
    __syncthreads();
#pragma unroll
    for (int hh = 0; hh < 2; hh++) {
      int kp = kl + hh * 8;
      float r = 0.f;
#pragma unroll
      for (int cc = 0; cc < C; cc++) r += P[kp][cc] * We[cc * C + c];
      out[((size_t)(g * K + sb * 16 + kp)) * C + c] = r;
    }
  }
}

extern "C" void kernel_launch(void* const* d_in, const int* in_sizes, int n_in,
                              void* d_out, int out_size, void* d_ws, size_t ws_size,
                              hipStream_t stream) {
  const float* f   = (const float*)d_in[0];
  const float* pos = (const float*)d_in[1];
  // d_in[2] = W_pool: mathematically unused (bias cancels in segment softmax)
  const float* Wr  = (const float*)d_in[3];
  const float* We  = (const float*)d_in[4];
  float* out = (float*)d_out;

  char* ws = (char*)d_ws;
  float*    partials = (float*)(ws + 0);          // [512][256][4] f32 = 2 MiB
  float*    kpts     = (float*)(ws + 2097152);    // [8][256] float4 = 32 KiB
  float*    gstat    = (float*)(ws + 2129920);    // [8] float4 (cx,cy,cz,maxdiam)
  unsigned* ghist    = (unsigned*)(ws + 2130432); // [8][512] u32 = 16 KiB
  unsigned* ccnt     = (unsigned*)(ws + 2146816); // [8] u32
  float4*   cand     = (float4*)(ws + 2147072);   // [8][4096] float4 = 512 KiB

  k_logits<<<dim3(BS * NSPL), dim3(256), 0, stream>>>(f, pos, Wr, partials);

  void* args[] = {(void*)&pos, (void*)&f, (void*)&We, (void*)&partials,
                  (void*)&kpts, (void*)&gstat, (void*)&ghist, (void*)&ccnt,
                  (void*)&cand, (void*)&out};
  hipLaunchCooperativeKernel((const void*)k_coop, dim3(BS * 16), dim3(256),
                             args, 0, stream);
}